// Round 20
// baseline (91.642 us; speedup 1.0000x reference)
//
#include <hip/hip_runtime.h>
#include <math.h>

#define NNODES 50000
#define NEDGES 800000
#define NBKT 196          // buckets of 256 rows (196*256 = 50176 >= N)
#define BKT_CAP 5120      // mean 4096, sigma ~64 -> +16 sigma headroom
#define EPB 2048          // edges per binA block
#define NBA ((NEDGES + EPB - 1) / EPB)   // 391 binA blocks
#define NBN ((NNODES + 127) / 128)       // 391 l0node blocks (128 rows, 512 thr)
#define NWP 64                           // wprep blocks

typedef __attribute__((ext_vector_type(8))) short short8;
typedef __attribute__((ext_vector_type(4))) float f32x4;

__device__ inline float bsum64(float v) {
    #pragma unroll
    for (int off = 1; off < 64; off <<= 1) v += __shfl_xor(v, off, 64);
    return v;
}

// pack two f32 -> 2x bf16 (RNE) in one uint (low short = a, high short = b)
__device__ inline unsigned packbf2(float a, float b) {
    unsigned ua = __float_as_uint(a);
    unsigned ub = __float_as_uint(b);
    ua = (ua + 0x7fffu + ((ua >> 16) & 1u)) >> 16;
    ub = (ub + 0x7fffu + ((ub >> 16) & 1u)) >> 16;
    return ua | (ub << 16);
}
__device__ inline float bflo(unsigned u) { return __uint_as_float(u << 16); }
__device__ inline float bfhi(unsigned u) { return __uint_as_float(u & 0xffff0000u); }

// ==== K2: wprep (blocks 0..63) || binA (blocks 64..) — 256 threads ====
__global__ __launch_bounds__(256) void k_prepA(const float* __restrict__ W,
                                               unsigned short* __restrict__ Whi,
                                               unsigned short* __restrict__ Wlo,
                                               const int* __restrict__ ei,
                                               int* __restrict__ gcur,
                                               unsigned* __restrict__ stag) {
    int t = threadIdx.x;
    if (blockIdx.x < NWP) {
        int tid = blockIdx.x * 256 + t;
        int i = tid & 7, lane = (tid >> 3) & 63, ct = (tid >> 9) & 7, kc = tid >> 12;
        int k = kc * 32 + (lane >> 4) * 8 + i;
        int col = ct * 16 + (lane & 15);
        float v = W[k * 128 + col];
        unsigned hb = packbf2(v, 0.f) & 0xffffu;
        float hv = __uint_as_float(hb << 16);
        unsigned lb = packbf2(v - hv, 0.f) & 0xffffu;
        Whi[tid] = (unsigned short)hb;
        Wlo[tid] = (unsigned short)lb;
        return;
    }
    __shared__ int lh[NBKT];
    __shared__ int lbase[NBKT];
    int blk = blockIdx.x - NWP;
    for (int i = t; i < NBKT; i += 256) lh[i] = 0;
    __syncthreads();
    int e0 = blk * EPB;
    int rows[8], cols[8];
    #pragma unroll
    for (int i = 0; i < 8; i++) {
        int e = e0 + i * 256 + t;
        if (e < NEDGES) {
            rows[i] = ei[e];
            cols[i] = ei[NEDGES + e];
            atomicAdd(&lh[rows[i] >> 8], 1);
        }
    }
    __syncthreads();
    for (int i = t; i < NBKT; i += 256) {
        lbase[i] = atomicAdd(&gcur[i], lh[i]);
        lh[i] = 0;
    }
    __syncthreads();
    #pragma unroll
    for (int i = 0; i < 8; i++) {
        int e = e0 + i * 256 + t;
        if (e < NEDGES) {
            int b = rows[i] >> 8;
            int rank = atomicAdd(&lh[b], 1);
            stag[b * BKT_CAP + lbase[b] + rank] =
                ((unsigned)(rows[i] & 255) << 16) | (unsigned)cols[i];
        }
    }
}

// ==== K3: 512 threads; l0node (blocks 0..NBN-1, LDS-staged W, 8 waves/128 rows)
//          || binC (blocks NBN.., 256-wide scans guarded) ====
__global__ __launch_bounds__(512) void k_nodeC(const float* __restrict__ x,
                                               const unsigned short* __restrict__ Whi,
                                               const unsigned short* __restrict__ Wlo,
                                               const float* __restrict__ attn0,
                                               float* __restrict__ ar,
                                               float* __restrict__ ac,
                                               unsigned* __restrict__ h0b,
                                               const int* __restrict__ gcur,
                                               const unsigned* __restrict__ stag,
                                               int* __restrict__ rowptr,
                                               int* __restrict__ ecol) {
    __shared__ uint4 shbuf[4096];   // 64KB: l0node W-stage; binC aliases as ints
    int t = threadIdx.x;

    if (blockIdx.x >= NBN) {
        // ---- binC: per-bucket rowptr + row-grouped ecol (512 threads) ----
        int b = blockIdx.x - NBN;
        int* sh = (int*)shbuf;
        int* dg = sh + 256;
        int* sc = dg + 256;
        int* cur = sc + 256;
        int* lout = cur + 256;   // BKT_CAP ints
        if (t < 256) sh[t] = (t < NBKT) ? gcur[t] : 0;
        __syncthreads();
        #pragma unroll
        for (int off = 1; off < 256; off <<= 1) {
            int u = (t >= off && t < 256) ? sh[t - off] : 0;
            __syncthreads();
            if (t < 256) sh[t] += u;
            __syncthreads();
        }
        int cnt = gcur[b];
        int base = sh[b] - cnt;
        if (t < 256) dg[t] = 0;
        __syncthreads();
        for (int i = t; i < cnt; i += 512)
            atomicAdd(&dg[stag[b * BKT_CAP + i] >> 16], 1);
        __syncthreads();
        int v = (t < 256) ? dg[t] : 0;
        if (t < 256) sc[t] = v;
        __syncthreads();
        #pragma unroll
        for (int off = 1; off < 256; off <<= 1) {
            int u = (t >= off && t < 256) ? sc[t - off] : 0;
            __syncthreads();
            if (t < 256) sc[t] += u;
            __syncthreads();
        }
        if (t < 256) {
            int excl = sc[t] - v;
            int gidx = b * 256 + t;
            if (gidx <= NNODES) rowptr[gidx] = base + excl;
            cur[t] = excl;
        }
        __syncthreads();
        for (int i = t; i < cnt; i += 512) {
            unsigned p = stag[b * BKT_CAP + i];
            int pos = atomicAdd(&cur[p >> 16], 1);
            lout[pos] = (int)(p & 0xffffu);
        }
        __syncthreads();
        for (int i = t; i < cnt; i += 512) ecol[base + i] = lout[i];
        return;
    }

    // ---- l0node: stage Whi/Wlo -> LDS once, serve 8 waves ----
    int bid = blockIdx.x;
    const uint4* WHg = (const uint4*)Whi;
    const uint4* WLg = (const uint4*)Wlo;
    #pragma unroll
    for (int i = 0; i < 4; i++) shbuf[i * 512 + t] = WHg[i * 512 + t];
    #pragma unroll
    for (int i = 0; i < 4; i++) shbuf[2048 + i * 512 + t] = WLg[i * 512 + t];
    __syncthreads();

    int w = t >> 6, lane = t & 63;
    int n0 = bid * 128 + w * 16;
    int c16 = lane & 15, grp = lane >> 4;
    int arow = n0 + c16;
    bool rowok = arow < NNODES;

    f32x4 acc[8];
    #pragma unroll
    for (int ct = 0; ct < 8; ct++) acc[ct] = (f32x4){0.f, 0.f, 0.f, 0.f};

    for (int kc = 0; kc < 4; kc++) {
        float xv[8];
        if (rowok) {
            *(float4*)&xv[0] = *(const float4*)&x[arow * 128 + kc * 32 + grp * 8];
            *(float4*)&xv[4] = *(const float4*)&x[arow * 128 + kc * 32 + grp * 8 + 4];
        } else {
            #pragma unroll
            for (int i = 0; i < 8; i++) xv[i] = 0.f;
        }
        unsigned ah[4];
        #pragma unroll
        for (int i = 0; i < 4; i++) ah[i] = packbf2(xv[2 * i], xv[2 * i + 1]);
        short8 a_h = *(short8*)ah;

        #pragma unroll
        for (int ct = 0; ct < 8; ct++) {
            uint4 whv = shbuf[(kc * 8 + ct) * 64 + lane];          // stride-1 b128, conflict-free
            uint4 wlv = shbuf[2048 + (kc * 8 + ct) * 64 + lane];
            short8 b_h = *(short8*)&whv;
            short8 b_l = *(short8*)&wlv;
            acc[ct] = __builtin_amdgcn_mfma_f32_16x16x32_bf16(a_h, b_h, acc[ct], 0, 0, 0);
            acc[ct] = __builtin_amdgcn_mfma_f32_16x16x32_bf16(a_h, b_l, acc[ct], 0, 0, 0);
        }
    }

    #pragma unroll
    for (int reg = 0; reg < 4; reg++) {
        float pr0 = 0.f, pc0 = 0.f, pr1 = 0.f, pc1 = 0.f;
        #pragma unroll
        for (int ct = 0; ct < 4; ct++) {
            float v = acc[ct][reg];
            int ch = ct * 16 + c16;
            pr0 += v * attn0[ch];
            pc0 += v * attn0[64 + ch];
        }
        #pragma unroll
        for (int ct = 4; ct < 8; ct++) {
            float v = acc[ct][reg];
            int ch = (ct - 4) * 16 + c16;
            pr1 += v * attn0[128 + ch];
            pc1 += v * attn0[192 + ch];
        }
        #pragma unroll
        for (int off = 1; off < 16; off <<= 1) {
            pr0 += __shfl_xor(pr0, off, 64);
            pc0 += __shfl_xor(pc0, off, 64);
            pr1 += __shfl_xor(pr1, off, 64);
            pc1 += __shfl_xor(pc1, off, 64);
        }
        int n = n0 + grp * 4 + reg;
        if (c16 == 0 && n < NNODES) {
            ar[n * 2] = pr0;     ac[n * 2] = pc0;
            ar[n * 2 + 1] = pr1; ac[n * 2 + 1] = pc1;
        }
    }

    #pragma unroll
    for (int reg = 0; reg < 4; reg++) {
        int n = n0 + grp * 4 + reg;
        if (n < NNODES) {
            #pragma unroll
            for (int ct = 0; ct < 4; ct++)
                h0b[n * 64 + ct * 16 + c16] = packbf2(acc[ct][reg], acc[ct + 4][reg]);
        }
    }
}

// ==== K4: layer 0 edge work (1 wave/node; branch-free gather, 4 loads in flight) ====
// inactive edge slots have p=0, colr=0 -> shfl'd q=0 makes the fma a no-op; loads are safe.
// shuffle index bound: tmax<=16 so (tt+k)*4+esub <= 15*4+3 = 63, always valid.
__global__ __launch_bounds__(256) void k_l0edge(const int* __restrict__ rowptr,
                                                const int* __restrict__ ecol,
                                                const float* __restrict__ ar,
                                                const float* __restrict__ ac,
                                                const unsigned* __restrict__ h0b,
                                                const float* __restrict__ W1,
                                                float* __restrict__ h1) {
    int w = threadIdx.x >> 6, lane = threadIdx.x & 63;
    int n = blockIdx.x * 4 + w;
    if (n >= NNODES) return;
    int beg = rowptr[n];
    int deg = rowptr[n + 1] - beg;
    float arn0 = ar[n * 2], arn1 = ar[n * 2 + 1];
    int esub = lane >> 4;
    int c16 = lane & 15;
    float accA[4] = {0.f, 0.f, 0.f, 0.f};
    float accB[4] = {0.f, 0.f, 0.f, 0.f};
    float s0t = 0.f, s1t = 0.f;
    for (int wb = 0; wb < deg; wb += 64) {
        int cnt = deg - wb; if (cnt > 64) cnt = 64;
        float p0 = 0.f, p1 = 0.f; int colr = 0;
        if (lane < cnt) {
            colr = ecol[beg + wb + lane];
            float2 acv = ((const float2*)ac)[colr];
            float a0 = arn0 + acv.x, a1 = arn1 + acv.y;
            a0 = a0 > 0.f ? a0 : 0.2f * a0;
            a1 = a1 > 0.f ? a1 : 0.2f * a1;
            p0 = __expf(a0); p1 = __expf(a1);
            s0t += p0; s1t += p1;
        }
        int tmax = (cnt + 3) >> 2;
        for (int tt = 0; tt < tmax; tt += 4) {
            int colv[4]; float q0v[4], q1v[4]; uint4 uv[4];
            #pragma unroll
            for (int k = 0; k < 4; k++) {
                int i4 = (tt + k) * 4 + esub;
                colv[k] = __shfl(colr, i4, 64);
                q0v[k] = __shfl(p0, i4, 64);
                q1v[k] = __shfl(p1, i4, 64);
            }
            #pragma unroll
            for (int k = 0; k < 4; k++)
                uv[k] = *(const uint4*)(h0b + colv[k] * 64 + c16 * 4);
            #pragma unroll
            for (int k = 0; k < 4; k++) {
                accA[0] += q0v[k] * bflo(uv[k].x); accB[0] += q1v[k] * bfhi(uv[k].x);
                accA[1] += q0v[k] * bflo(uv[k].y); accB[1] += q1v[k] * bfhi(uv[k].y);
                accA[2] += q0v[k] * bflo(uv[k].z); accB[2] += q1v[k] * bfhi(uv[k].z);
                accA[3] += q0v[k] * bflo(uv[k].w); accB[3] += q1v[k] * bfhi(uv[k].w);
            }
        }
    }
    float s0 = bsum64(s0t), s1 = bsum64(s1t);
    #pragma unroll
    for (int jj = 0; jj < 4; jj++) {
        accA[jj] += __shfl_xor(accA[jj], 16, 64);
        accA[jj] += __shfl_xor(accA[jj], 32, 64);
        accB[jj] += __shfl_xor(accB[jj], 16, 64);
        accB[jj] += __shfl_xor(accB[jj], 32, 64);
    }
    float si0 = deg ? 0.5f / s0 : 0.f;
    float si1 = deg ? 0.5f / s1 : 0.f;
    float pA = 0.f, pB = 0.f;
    #pragma unroll
    for (int jj = 0; jj < 4; jj++) {
        float o = si0 * accA[jj] + si1 * accB[jj];
        o = o > 0.f ? o : 0.f;   // relu
        float2 wv = ((const float2*)W1)[c16 * 4 + jj];
        pA += o * wv.x; pB += o * wv.y;
    }
    #pragma unroll
    for (int off = 1; off < 16; off <<= 1) {
        pA += __shfl_xor(pA, off, 64);
        pB += __shfl_xor(pB, off, 64);
    }
    if (lane == 0) { h1[n * 2] = pA; h1[n * 2 + 1] = pB; }
}

// ==== K5: layer 1 fused ====
__global__ __launch_bounds__(256) void k_fused1(const int* __restrict__ rowptr,
                                                const int* __restrict__ ecol,
                                                const float* __restrict__ h1,
                                                const float* __restrict__ attn1,
                                                float* __restrict__ dout) {
    int w = threadIdx.x >> 6, lane = threadIdx.x & 63;
    int n = blockIdx.x * 4 + w;
    if (n >= NNODES) return;
    int beg = rowptr[n], end = rowptr[n + 1];
    if (beg == end) { if (lane == 0) dout[n] = 0.f; return; }
    float w01 = attn1[1], w11 = attn1[3];
    float base0 = attn1[0] * h1[n * 2];
    float base1 = attn1[2] * h1[n * 2 + 1];
    float s0 = 0.f, s1 = 0.f, acc0 = 0.f, acc1 = 0.f;
    for (int i = beg + lane; i < end; i += 64) {
        int col = ecol[i];
        float2 v = ((const float2*)h1)[col];
        float a0 = base0 + w01 * v.x;
        float a1 = base1 + w11 * v.y;
        a0 = a0 > 0.f ? a0 : 0.2f * a0;
        a1 = a1 > 0.f ? a1 : 0.2f * a1;
        float p0 = __expf(a0), p1 = __expf(a1);
        s0 += p0; acc0 += p0 * v.x;
        s1 += p1; acc1 += p1 * v.y;
    }
    s0 = bsum64(s0); s1 = bsum64(s1);
    acc0 = bsum64(acc0); acc1 = bsum64(acc1);
    if (lane == 0) dout[n] = 0.5f * (acc0 / s0 + acc1 / s1);
}

extern "C" void kernel_launch(void* const* d_in, const int* in_sizes, int n_in,
                              void* d_out, int out_size, void* d_ws, size_t ws_size,
                              hipStream_t stream) {
    const float* x     = (const float*)d_in[0];
    const int*   ei    = (const int*)d_in[1];
    const float* W0    = (const float*)d_in[2];
    const float* attn0 = (const float*)d_in[3];
    const float* W1    = (const float*)d_in[4];
    const float* attn1 = (const float*)d_in[5];
    float* dout = (float*)d_out;

    float* ws = (float*)d_ws;
    float*          ar     = ws;                             // N*2
    float*          ac     = ar + NNODES * 2;                // N*2
    float*          h1     = ac + NNODES * 2;                // N*2
    unsigned*       h0b    = (unsigned*)(h1 + NNODES * 2);   // N*64
    unsigned short* Whi    = (unsigned short*)(h0b + NNODES * 64); // 128*128
    unsigned short* Wlo    = Whi + 128 * 128;                // 128*128
    int*            gcur   = (int*)(Wlo + 128 * 128);        // NBKT
    int*            rowptr = gcur + NBKT;                    // N+1
    unsigned*       stag   = (unsigned*)(rowptr + NNODES + 1); // NBKT*BKT_CAP
    int*            ecol   = (int*)(stag + NBKT * BKT_CAP);  // E

    hipMemsetAsync(gcur, 0, NBKT * sizeof(int), stream);
    // K2: wprep (64) || binA (391)
    k_prepA<<<NWP + NBA, 256, 0, stream>>>(W0, Whi, Wlo, ei, gcur, stag);
    // K3 (512 thr): l0node (391, LDS-staged W, 8 waves) || binC (196)
    k_nodeC<<<NBN + NBKT, 512, 0, stream>>>(x, Whi, Wlo, attn0, ar, ac, h0b,
                                            gcur, stag, rowptr, ecol);
    // K4: layer-0 edge work (4 gathers in flight)
    k_l0edge<<<(NNODES + 3) / 4, 256, 0, stream>>>(rowptr, ecol, ar, ac, h0b, W1, h1);
    // K5: layer-1
    k_fused1<<<(NNODES + 3) / 4, 256, 0, stream>>>(rowptr, ecol, h1, attn1, dout);
}

// Round 21
// 88.788 us; speedup vs baseline: 1.0321x; 1.0321x over previous
//
#include <hip/hip_runtime.h>
#include <math.h>

#define NNODES 50000
#define NEDGES 800000
#define NBKT 196          // buckets of 256 rows (196*256 = 50176 >= N)
#define BKT_CAP 5120      // mean 4096, sigma ~64 -> +16 sigma headroom
#define EPB 2048          // edges per binA block
#define NBA ((NEDGES + EPB - 1) / EPB)   // 391 binA blocks
#define NBN ((NNODES + 127) / 128)       // 391 l0node blocks (128 rows, 512 thr)
#define NWP 64                           // wprep blocks

typedef __attribute__((ext_vector_type(8))) short short8;
typedef __attribute__((ext_vector_type(4))) float f32x4;

__device__ inline float bsum64(float v) {
    #pragma unroll
    for (int off = 1; off < 64; off <<= 1) v += __shfl_xor(v, off, 64);
    return v;
}

// pack two f32 -> 2x bf16 (RNE) in one uint (low short = a, high short = b)
__device__ inline unsigned packbf2(float a, float b) {
    unsigned ua = __float_as_uint(a);
    unsigned ub = __float_as_uint(b);
    ua = (ua + 0x7fffu + ((ua >> 16) & 1u)) >> 16;
    ub = (ub + 0x7fffu + ((ub >> 16) & 1u)) >> 16;
    return ua | (ub << 16);
}
__device__ inline float bflo(unsigned u) { return __uint_as_float(u << 16); }
__device__ inline float bfhi(unsigned u) { return __uint_as_float(u & 0xffff0000u); }

// ==== K2: wprep (blocks 0..63) || binA (blocks 64..) — 256 threads ====
__global__ __launch_bounds__(256) void k_prepA(const float* __restrict__ W,
                                               unsigned short* __restrict__ Whi,
                                               unsigned short* __restrict__ Wlo,
                                               const int* __restrict__ ei,
                                               int* __restrict__ gcur,
                                               unsigned* __restrict__ stag) {
    int t = threadIdx.x;
    if (blockIdx.x < NWP) {
        int tid = blockIdx.x * 256 + t;
        int i = tid & 7, lane = (tid >> 3) & 63, ct = (tid >> 9) & 7, kc = tid >> 12;
        int k = kc * 32 + (lane >> 4) * 8 + i;
        int col = ct * 16 + (lane & 15);
        float v = W[k * 128 + col];
        unsigned hb = packbf2(v, 0.f) & 0xffffu;
        float hv = __uint_as_float(hb << 16);
        unsigned lb = packbf2(v - hv, 0.f) & 0xffffu;
        Whi[tid] = (unsigned short)hb;
        Wlo[tid] = (unsigned short)lb;
        return;
    }
    __shared__ int lh[NBKT];
    __shared__ int lbase[NBKT];
    int blk = blockIdx.x - NWP;
    for (int i = t; i < NBKT; i += 256) lh[i] = 0;
    __syncthreads();
    int e0 = blk * EPB;
    int rows[8], cols[8];
    #pragma unroll
    for (int i = 0; i < 8; i++) {
        int e = e0 + i * 256 + t;
        if (e < NEDGES) {
            rows[i] = ei[e];
            cols[i] = ei[NEDGES + e];
            atomicAdd(&lh[rows[i] >> 8], 1);
        }
    }
    __syncthreads();
    for (int i = t; i < NBKT; i += 256) {
        lbase[i] = atomicAdd(&gcur[i], lh[i]);
        lh[i] = 0;
    }
    __syncthreads();
    #pragma unroll
    for (int i = 0; i < 8; i++) {
        int e = e0 + i * 256 + t;
        if (e < NEDGES) {
            int b = rows[i] >> 8;
            int rank = atomicAdd(&lh[b], 1);
            stag[b * BKT_CAP + lbase[b] + rank] =
                ((unsigned)(rows[i] & 255) << 16) | (unsigned)cols[i];
        }
    }
}

// ==== K3: 512 threads; l0node (blocks 0..NBN-1, LDS-staged W, 8 waves/128 rows)
//          || binC (blocks NBN.., 256-wide scans guarded) ====
__global__ __launch_bounds__(512) void k_nodeC(const float* __restrict__ x,
                                               const unsigned short* __restrict__ Whi,
                                               const unsigned short* __restrict__ Wlo,
                                               const float* __restrict__ attn0,
                                               float* __restrict__ ar,
                                               float* __restrict__ ac,
                                               unsigned* __restrict__ h0b,
                                               const int* __restrict__ gcur,
                                               const unsigned* __restrict__ stag,
                                               int* __restrict__ rowptr,
                                               int* __restrict__ ecol) {
    __shared__ uint4 shbuf[4096];   // 64KB: l0node W-stage; binC aliases as ints
    int t = threadIdx.x;

    if (blockIdx.x >= NBN) {
        // ---- binC: per-bucket rowptr + row-grouped ecol (512 threads) ----
        int b = blockIdx.x - NBN;
        int* sh = (int*)shbuf;
        int* dg = sh + 256;
        int* sc = dg + 256;
        int* cur = sc + 256;
        int* lout = cur + 256;   // BKT_CAP ints
        if (t < 256) sh[t] = (t < NBKT) ? gcur[t] : 0;
        __syncthreads();
        #pragma unroll
        for (int off = 1; off < 256; off <<= 1) {
            int u = (t >= off && t < 256) ? sh[t - off] : 0;
            __syncthreads();
            if (t < 256) sh[t] += u;
            __syncthreads();
        }
        int cnt = gcur[b];
        int base = sh[b] - cnt;
        if (t < 256) dg[t] = 0;
        __syncthreads();
        for (int i = t; i < cnt; i += 512)
            atomicAdd(&dg[stag[b * BKT_CAP + i] >> 16], 1);
        __syncthreads();
        int v = (t < 256) ? dg[t] : 0;
        if (t < 256) sc[t] = v;
        __syncthreads();
        #pragma unroll
        for (int off = 1; off < 256; off <<= 1) {
            int u = (t >= off && t < 256) ? sc[t - off] : 0;
            __syncthreads();
            if (t < 256) sc[t] += u;
            __syncthreads();
        }
        if (t < 256) {
            int excl = sc[t] - v;
            int gidx = b * 256 + t;
            if (gidx <= NNODES) rowptr[gidx] = base + excl;
            cur[t] = excl;
        }
        __syncthreads();
        for (int i = t; i < cnt; i += 512) {
            unsigned p = stag[b * BKT_CAP + i];
            int pos = atomicAdd(&cur[p >> 16], 1);
            lout[pos] = (int)(p & 0xffffu);
        }
        __syncthreads();
        for (int i = t; i < cnt; i += 512) ecol[base + i] = lout[i];
        return;
    }

    // ---- l0node: stage Whi/Wlo -> LDS once, serve 8 waves ----
    int bid = blockIdx.x;
    const uint4* WHg = (const uint4*)Whi;
    const uint4* WLg = (const uint4*)Wlo;
    #pragma unroll
    for (int i = 0; i < 4; i++) shbuf[i * 512 + t] = WHg[i * 512 + t];
    #pragma unroll
    for (int i = 0; i < 4; i++) shbuf[2048 + i * 512 + t] = WLg[i * 512 + t];
    __syncthreads();

    int w = t >> 6, lane = t & 63;
    int n0 = bid * 128 + w * 16;
    int c16 = lane & 15, grp = lane >> 4;
    int arow = n0 + c16;
    bool rowok = arow < NNODES;

    f32x4 acc[8];
    #pragma unroll
    for (int ct = 0; ct < 8; ct++) acc[ct] = (f32x4){0.f, 0.f, 0.f, 0.f};

    for (int kc = 0; kc < 4; kc++) {
        float xv[8];
        if (rowok) {
            *(float4*)&xv[0] = *(const float4*)&x[arow * 128 + kc * 32 + grp * 8];
            *(float4*)&xv[4] = *(const float4*)&x[arow * 128 + kc * 32 + grp * 8 + 4];
        } else {
            #pragma unroll
            for (int i = 0; i < 8; i++) xv[i] = 0.f;
        }
        unsigned ah[4];
        #pragma unroll
        for (int i = 0; i < 4; i++) ah[i] = packbf2(xv[2 * i], xv[2 * i + 1]);
        short8 a_h = *(short8*)ah;

        #pragma unroll
        for (int ct = 0; ct < 8; ct++) {
            uint4 whv = shbuf[(kc * 8 + ct) * 64 + lane];          // stride-1 b128, conflict-free
            uint4 wlv = shbuf[2048 + (kc * 8 + ct) * 64 + lane];
            short8 b_h = *(short8*)&whv;
            short8 b_l = *(short8*)&wlv;
            acc[ct] = __builtin_amdgcn_mfma_f32_16x16x32_bf16(a_h, b_h, acc[ct], 0, 0, 0);
            acc[ct] = __builtin_amdgcn_mfma_f32_16x16x32_bf16(a_h, b_l, acc[ct], 0, 0, 0);
        }
    }

    #pragma unroll
    for (int reg = 0; reg < 4; reg++) {
        float pr0 = 0.f, pc0 = 0.f, pr1 = 0.f, pc1 = 0.f;
        #pragma unroll
        for (int ct = 0; ct < 4; ct++) {
            float v = acc[ct][reg];
            int ch = ct * 16 + c16;
            pr0 += v * attn0[ch];
            pc0 += v * attn0[64 + ch];
        }
        #pragma unroll
        for (int ct = 4; ct < 8; ct++) {
            float v = acc[ct][reg];
            int ch = (ct - 4) * 16 + c16;
            pr1 += v * attn0[128 + ch];
            pc1 += v * attn0[192 + ch];
        }
        #pragma unroll
        for (int off = 1; off < 16; off <<= 1) {
            pr0 += __shfl_xor(pr0, off, 64);
            pc0 += __shfl_xor(pc0, off, 64);
            pr1 += __shfl_xor(pr1, off, 64);
            pc1 += __shfl_xor(pc1, off, 64);
        }
        int n = n0 + grp * 4 + reg;
        if (c16 == 0 && n < NNODES) {
            ar[n * 2] = pr0;     ac[n * 2] = pc0;
            ar[n * 2 + 1] = pr1; ac[n * 2 + 1] = pc1;
        }
    }

    #pragma unroll
    for (int reg = 0; reg < 4; reg++) {
        int n = n0 + grp * 4 + reg;
        if (n < NNODES) {
            #pragma unroll
            for (int ct = 0; ct < 4; ct++)
                h0b[n * 64 + ct * 16 + c16] = packbf2(acc[ct][reg], acc[ct + 4][reg]);
        }
    }
}

// ==== K4: layer 0 edge work (1 wave/node; branch-free gather, 2 loads in flight) ====
// inactive edge slots have p=0, colr=0 -> shfl'd q=0 makes the fma a no-op; loads are safe.
__global__ __launch_bounds__(256) void k_l0edge(const int* __restrict__ rowptr,
                                                const int* __restrict__ ecol,
                                                const float* __restrict__ ar,
                                                const float* __restrict__ ac,
                                                const unsigned* __restrict__ h0b,
                                                const float* __restrict__ W1,
                                                float* __restrict__ h1) {
    int w = threadIdx.x >> 6, lane = threadIdx.x & 63;
    int n = blockIdx.x * 4 + w;
    if (n >= NNODES) return;
    int beg = rowptr[n];
    int deg = rowptr[n + 1] - beg;
    float arn0 = ar[n * 2], arn1 = ar[n * 2 + 1];
    int esub = lane >> 4;
    int c16 = lane & 15;
    float accA[4] = {0.f, 0.f, 0.f, 0.f};
    float accB[4] = {0.f, 0.f, 0.f, 0.f};
    float s0t = 0.f, s1t = 0.f;
    for (int wb = 0; wb < deg; wb += 64) {
        int cnt = deg - wb; if (cnt > 64) cnt = 64;
        float p0 = 0.f, p1 = 0.f; int colr = 0;
        if (lane < cnt) {
            colr = ecol[beg + wb + lane];
            float2 acv = ((const float2*)ac)[colr];
            float a0 = arn0 + acv.x, a1 = arn1 + acv.y;
            a0 = a0 > 0.f ? a0 : 0.2f * a0;
            a1 = a1 > 0.f ? a1 : 0.2f * a1;
            p0 = __expf(a0); p1 = __expf(a1);
            s0t += p0; s1t += p1;
        }
        int tmax = (cnt + 3) >> 2;
        int tt = 0;
        for (; tt + 2 <= tmax; tt += 2) {
            int ia = tt * 4 + esub, ib = ia + 4;
            int colA = __shfl(colr, ia, 64);
            int colB = __shfl(colr, ib, 64);
            float qa0 = __shfl(p0, ia, 64), qa1 = __shfl(p1, ia, 64);
            float qb0 = __shfl(p0, ib, 64), qb1 = __shfl(p1, ib, 64);
            const uint4 uA = *(const uint4*)(h0b + colA * 64 + c16 * 4);
            const uint4 uB = *(const uint4*)(h0b + colB * 64 + c16 * 4);
            accA[0] += qa0 * bflo(uA.x); accB[0] += qa1 * bfhi(uA.x);
            accA[1] += qa0 * bflo(uA.y); accB[1] += qa1 * bfhi(uA.y);
            accA[2] += qa0 * bflo(uA.z); accB[2] += qa1 * bfhi(uA.z);
            accA[3] += qa0 * bflo(uA.w); accB[3] += qa1 * bfhi(uA.w);
            accA[0] += qb0 * bflo(uB.x); accB[0] += qb1 * bfhi(uB.x);
            accA[1] += qb0 * bflo(uB.y); accB[1] += qb1 * bfhi(uB.y);
            accA[2] += qb0 * bflo(uB.z); accB[2] += qb1 * bfhi(uB.z);
            accA[3] += qb0 * bflo(uB.w); accB[3] += qb1 * bfhi(uB.w);
        }
        if (tt < tmax) {
            int ia = tt * 4 + esub;
            int colA = __shfl(colr, ia, 64);
            float qa0 = __shfl(p0, ia, 64), qa1 = __shfl(p1, ia, 64);
            const uint4 uA = *(const uint4*)(h0b + colA * 64 + c16 * 4);
            accA[0] += qa0 * bflo(uA.x); accB[0] += qa1 * bfhi(uA.x);
            accA[1] += qa0 * bflo(uA.y); accB[1] += qa1 * bfhi(uA.y);
            accA[2] += qa0 * bflo(uA.z); accB[2] += qa1 * bfhi(uA.z);
            accA[3] += qa0 * bflo(uA.w); accB[3] += qa1 * bfhi(uA.w);
        }
    }
    float s0 = bsum64(s0t), s1 = bsum64(s1t);
    #pragma unroll
    for (int jj = 0; jj < 4; jj++) {
        accA[jj] += __shfl_xor(accA[jj], 16, 64);
        accA[jj] += __shfl_xor(accA[jj], 32, 64);
        accB[jj] += __shfl_xor(accB[jj], 16, 64);
        accB[jj] += __shfl_xor(accB[jj], 32, 64);
    }
    float si0 = deg ? 0.5f / s0 : 0.f;
    float si1 = deg ? 0.5f / s1 : 0.f;
    float pA = 0.f, pB = 0.f;
    #pragma unroll
    for (int jj = 0; jj < 4; jj++) {
        float o = si0 * accA[jj] + si1 * accB[jj];
        o = o > 0.f ? o : 0.f;   // relu
        float2 wv = ((const float2*)W1)[c16 * 4 + jj];
        pA += o * wv.x; pB += o * wv.y;
    }
    #pragma unroll
    for (int off = 1; off < 16; off <<= 1) {
        pA += __shfl_xor(pA, off, 64);
        pB += __shfl_xor(pB, off, 64);
    }
    if (lane == 0) { h1[n * 2] = pA; h1[n * 2 + 1] = pB; }
}

// ==== K5: layer 1 fused ====
__global__ __launch_bounds__(256) void k_fused1(const int* __restrict__ rowptr,
                                                const int* __restrict__ ecol,
                                                const float* __restrict__ h1,
                                                const float* __restrict__ attn1,
                                                float* __restrict__ dout) {
    int w = threadIdx.x >> 6, lane = threadIdx.x & 63;
    int n = blockIdx.x * 4 + w;
    if (n >= NNODES) return;
    int beg = rowptr[n], end = rowptr[n + 1];
    if (beg == end) { if (lane == 0) dout[n] = 0.f; return; }
    float w01 = attn1[1], w11 = attn1[3];
    float base0 = attn1[0] * h1[n * 2];
    float base1 = attn1[2] * h1[n * 2 + 1];
    float s0 = 0.f, s1 = 0.f, acc0 = 0.f, acc1 = 0.f;
    for (int i = beg + lane; i < end; i += 64) {
        int col = ecol[i];
        float2 v = ((const float2*)h1)[col];
        float a0 = base0 + w01 * v.x;
        float a1 = base1 + w11 * v.y;
        a0 = a0 > 0.f ? a0 : 0.2f * a0;
        a1 = a1 > 0.f ? a1 : 0.2f * a1;
        float p0 = __expf(a0), p1 = __expf(a1);
        s0 += p0; acc0 += p0 * v.x;
        s1 += p1; acc1 += p1 * v.y;
    }
    s0 = bsum64(s0); s1 = bsum64(s1);
    acc0 = bsum64(acc0); acc1 = bsum64(acc1);
    if (lane == 0) dout[n] = 0.5f * (acc0 / s0 + acc1 / s1);
}

extern "C" void kernel_launch(void* const* d_in, const int* in_sizes, int n_in,
                              void* d_out, int out_size, void* d_ws, size_t ws_size,
                              hipStream_t stream) {
    const float* x     = (const float*)d_in[0];
    const int*   ei    = (const int*)d_in[1];
    const float* W0    = (const float*)d_in[2];
    const float* attn0 = (const float*)d_in[3];
    const float* W1    = (const float*)d_in[4];
    const float* attn1 = (const float*)d_in[5];
    float* dout = (float*)d_out;

    float* ws = (float*)d_ws;
    float*          ar     = ws;                             // N*2
    float*          ac     = ar + NNODES * 2;                // N*2
    float*          h1     = ac + NNODES * 2;                // N*2
    unsigned*       h0b    = (unsigned*)(h1 + NNODES * 2);   // N*64
    unsigned short* Whi    = (unsigned short*)(h0b + NNODES * 64); // 128*128
    unsigned short* Wlo    = Whi + 128 * 128;                // 128*128
    int*            gcur   = (int*)(Wlo + 128 * 128);        // NBKT
    int*            rowptr = gcur + NBKT;                    // N+1
    unsigned*       stag   = (unsigned*)(rowptr + NNODES + 1); // NBKT*BKT_CAP
    int*            ecol   = (int*)(stag + NBKT * BKT_CAP);  // E

    hipMemsetAsync(gcur, 0, NBKT * sizeof(int), stream);
    // K2: wprep (64) || binA (391)
    k_prepA<<<NWP + NBA, 256, 0, stream>>>(W0, Whi, Wlo, ei, gcur, stag);
    // K3 (512 thr): l0node (391, LDS-staged W, 8 waves) || binC (196)
    k_nodeC<<<NBN + NBKT, 512, 0, stream>>>(x, Whi, Wlo, attn0, ar, ac, h0b,
                                            gcur, stag, rowptr, ecol);
    // K4: layer-0 edge work (2 gathers in flight)
    k_l0edge<<<(NNODES + 3) / 4, 256, 0, stream>>>(rowptr, ecol, ar, ac, h0b, W1, h1);
    // K5: layer-1
    k_fused1<<<(NNODES + 3) / 4, 256, 0, stream>>>(rowptr, ecol, h1, attn1, dout);
}